// Round 9
// baseline (400.268 us; speedup 1.0000x reference)
//
#include <hip/hip_runtime.h>

typedef __attribute__((ext_vector_type(8))) __bf16 bf16x8;
typedef __attribute__((ext_vector_type(4))) float f32x4;

#define N_ 1024
#define C_ 64
#define BP_ 48

static __device__ __forceinline__ unsigned short f2bf(float f) {
    __bf16 b = (__bf16)f;
    return __builtin_bit_cast(unsigned short, b);
}
static __device__ __forceinline__ unsigned int pack2(float a, float b) {
    return (unsigned int)f2bf(a) | ((unsigned int)f2bf(b) << 16);
}
// global->LDS DMA, 16B/lane: LDS gets wave-uniform base + 16*lane
static __device__ __forceinline__ void load_lds16(const void* g, void* s) {
    __builtin_amdgcn_global_load_lds(
        (__attribute__((address_space(1))) void*)g,
        (__attribute__((address_space(3))) void*)s, 16, 0, 0);
}

// ---------------------------------------------------------------------------
// K1: v1/v2 fold of W_emb, s1/s2 per node, per-wave max(s2) -> M2part, and
// xT in MFMA-FRAGMENT order: [bp][chunk jc][s][nt][q][i15][8 bf16], so the
// main kernel's LDS-staged B-frag reads are stride-1 16B (conflict-free) and
// DMA-compatible (no padding).  grid (16 j-chunks, 48 bp), block 256.
// ---------------------------------------------------------------------------
__global__ __launch_bounds__(256) void gat_pre(
    const float* __restrict__ x, const float* __restrict__ Wemb,
    const float* __restrict__ a1, const float* __restrict__ a2,
    float* __restrict__ s1g, float* __restrict__ s2g,
    unsigned short* __restrict__ xT, float* __restrict__ M2part)
{
    __shared__ float xs[64][65];
    __shared__ float vs[2][64];
    const int t = threadIdx.x, l = t & 63, w = t >> 6;
    const int j0 = blockIdx.x * 64;
    const int bp = blockIdx.y;

    if (w == 0) {   // v1[c]=sum_h a1[h]*W_emb[h][c]  (x_emb folds away)
        float v1 = 0.f, v2 = 0.f;
        #pragma unroll 8
        for (int h = 0; h < 64; ++h) {
            float we = Wemb[h * 64 + l];
            v1 = fmaf(a1[h], we, v1);
            v2 = fmaf(a2[h], we, v2);
        }
        vs[0][l] = v1; vs[1][l] = v2;
    }
    const float* xb = x + ((size_t)bp * N_ + j0) * C_;
    #pragma unroll
    for (int it = 0; it < 16; ++it)
        xs[it * 4 + w][l] = xb[(it * 4 + w) * C_ + l];
    __syncthreads();

    const int jr = t >> 2, c0 = (t & 3) * 16;
    float p1 = 0.f, p2 = 0.f;
    #pragma unroll
    for (int k = 0; k < 16; ++k) {
        float xv = xs[jr][c0 + k];
        p1 = fmaf(xv, vs[0][c0 + k], p1);
        p2 = fmaf(xv, vs[1][c0 + k], p2);
    }
    p1 += __shfl_xor(p1, 1); p1 += __shfl_xor(p1, 2);
    p2 += __shfl_xor(p2, 1); p2 += __shfl_xor(p2, 2);
    if ((l & 3) == 0) {
        s1g[bp * N_ + j0 + jr] = p1;
        s2g[bp * N_ + j0 + jr] = p2;
    }
    float m = p2;
    m = fmaxf(m, __shfl_xor(m, 4));
    m = fmaxf(m, __shfl_xor(m, 8));
    m = fmaxf(m, __shfl_xor(m, 16));
    m = fmaxf(m, __shfl_xor(m, 32));
    if (l == 0) M2part[bp * 64 + blockIdx.x * 4 + w] = m;

    // fragment-order bf16 output: thread t -> (i15,q,nt), two s values.
    // frag elem k = x[j = s*32+q*8+k][c = nt*16+i15]
    const int i15p = t & 15, qp = (t >> 4) & 3, ntp = t >> 6;
    uint4* xf = (uint4*)xT;
    const size_t cbase = ((size_t)bp * 16 + blockIdx.x) * 512;
    #pragma unroll
    for (int s = 0; s < 2; ++s) {
        unsigned int dw[4];
        #pragma unroll
        for (int d = 0; d < 4; ++d)
            dw[d] = pack2(xs[s * 32 + qp * 8 + 2 * d][ntp * 16 + i15p],
                          xs[s * 32 + qp * 8 + 2 * d + 1][ntp * 16 + i15p]);
        xf[cbase + s * 256 + ntp * 64 + qp * 16 + i15p] =
            make_uint4(dw[0], dw[1], dw[2], dw[3]);
    }
}

// ---------------------------------------------------------------------------
// K2 (fused, all-DMA pipeline): the K-loop's ONLY vmem ops are DMA prefetch
// (A chunk per wave + xT chunk shared) and A-passthrough stores — no in-loop
// vmem CONSUMER exists, so nothing forces the prefetch to drain early (R8
// failure: xT global loads inside the loop FIFO-coupled to the DMA).
// Raw  s_waitcnt vmcnt(0); s_barrier  per chunk — waits DMA(k) issued a full
// iteration ago, NOT DMA(k+1) issued after the barrier.  Barrier also
// guards the double-buffer WAR (chunk k-1 reads done before DMA(k+1)).
// grid (16,48), block 256 = 4 waves x 16 rows; 62.7KB LDS -> 2 blocks/CU.
// ---------------------------------------------------------------------------
__global__ __launch_bounds__(256) void gat_fused(
    const float* __restrict__ Ag, float* __restrict__ outA,
    const unsigned short* __restrict__ xT,
    const float* __restrict__ s1g, const float* __restrict__ s2g,
    const float* __restrict__ M2part,
    const float* __restrict__ Wlin, float* __restrict__ out)
{
    __shared__ float Abuf[2][4][1024];          // 32 KB [buf][wave][16r x 64j]
    __shared__ uint4 Xbuf[2][512];              // 16 KB [buf][frag s,nt,q,i15]
    __shared__ float s2lds[1024];               //  4 KB
    __shared__ unsigned short Plds[4][16][72];  //  9 KB per-wave P (pad 8)
    __shared__ float lsLDS[4][16];              //  256 B

    const int t = threadIdx.x, l = t & 63, w = t >> 6;
    const int i15 = l & 15, q = l >> 4;
    const int lm = l & 15, g16 = l >> 4;
    const int bp = blockIdx.y;
    const int ibase = blockIdx.x * 64 + w * 16;

    *(f32x4*)&s2lds[4 * t] = *(const f32x4*)&s2g[bp * N_ + 4 * t];

    float m2v = M2part[bp * 64 + l];
    #pragma unroll
    for (int off = 32; off >= 1; off >>= 1)
        m2v = fmaxf(m2v, __shfl_xor(m2v, off));
    const float M2 = m2v;
    const float s1_l = s1g[bp * N_ + ibase + i15];   // lane rr holds s1 of row rr

    __syncthreads();   // s2lds ready; full drain OK here (before any DMA)

    const float* Arow = Ag + (size_t)bp * N_ * N_ + (size_t)ibase * N_;
    float* oArow = outA + (size_t)bp * N_ * N_ + (size_t)ibase * N_;
    const uint4* xf = (const uint4*)xT + (size_t)bp * 16 * 512;  // frag chunks

    f32x4 acc[4] = {};
    float ls4[4] = {0.f, 0.f, 0.f, 0.f};

    // prime: chunk 0 -> buf 0.  A: wave's own 16 rows (4 instr).
    // xT: shared 512 frags, wave w stages instr m=2w,2w+1 (64 frags each).
    #pragma unroll
    for (int r4 = 0; r4 < 4; ++r4)
        load_lds16(&Arow[(size_t)(4 * r4 + g16) * N_ + 4 * lm],
                   &Abuf[0][w][r4 * 256]);
    #pragma unroll
    for (int mi = 0; mi < 2; ++mi)
        load_lds16(&xf[(size_t)(2 * w + mi) * 64 + l],
                   &Xbuf[0][(2 * w + mi) * 64]);

    #pragma unroll 2
    for (int k = 0; k < 16; ++k) {
        const int cb = k & 1, j0c = k * 64;
        // own chunk-k DMA arrived (+ old stores flushed), then all waves'
        asm volatile("s_waitcnt vmcnt(0)\n\ts_barrier" ::: "memory");
        if (k < 15) {   // issue chunk k+1 DMA into the other buffer
            #pragma unroll
            for (int r4 = 0; r4 < 4; ++r4)
                load_lds16(&Arow[(size_t)(4 * r4 + g16) * N_ + j0c + 64 + 4 * lm],
                           &Abuf[cb ^ 1][w][r4 * 256]);
            #pragma unroll
            for (int mi = 0; mi < 2; ++mi)
                load_lds16(&xf[(size_t)(k + 1) * 512 + (2 * w + mi) * 64 + l],
                           &Xbuf[cb ^ 1][(2 * w + mi) * 64]);
        }
        const f32x4 s2v = *(const f32x4*)&s2lds[j0c + 4 * lm];
        #pragma unroll
        for (int sr = 0; sr < 4; ++sr) {    // consume rows 4sr+g16, cols 4lm
            f32x4 Av = *(const f32x4*)&Abuf[cb][w][sr * 256 + 4 * l];
            *(f32x4*)&oArow[(size_t)(4 * sr + g16) * N_ + j0c + 4 * lm] = Av;
            float s1v = __shfl(s1_l, 4 * sr + g16);
            float zr = s1v + M2;
            float mv = fmaxf(zr, 0.01f * zr);       // fixed softmax shift
            float e[4];
            #pragma unroll
            for (int kk = 0; kk < 4; ++kk) {
                float zz = s1v + s2v[kk];
                zz = fmaxf(zz, 0.01f * zz);         // leaky_relu
                e[kk] = (Av[kk] != 0.f) ? __expf(zz - mv) : 0.f;
            }
            ls4[sr] += (e[0] + e[1]) + (e[2] + e[3]);
            *(uint2*)&Plds[w][4 * sr + g16][4 * lm] =
                make_uint2(pack2(e[0], e[1]), pack2(e[2], e[3]));
        }
        // acc += P_chunk @ X_chunk  (M16 x N64 x K64; B-frags stride-1 LDS)
        #pragma unroll
        for (int s = 0; s < 2; ++s) {
            bf16x8 af = *(const bf16x8*)&Plds[w][i15][s * 32 + q * 8];
            #pragma unroll
            for (int nt = 0; nt < 4; ++nt) {
                bf16x8 bfr = *(const bf16x8*)&Xbuf[cb][s * 256 + nt * 64 + q * 16 + i15];
                acc[nt] = __builtin_amdgcn_mfma_f32_16x16x32_bf16(af, bfr, acc[nt], 0, 0, 0);
            }
        }
    }

    // lsum: reduce within 16-lane group, exchange via LDS (constant indices)
    #pragma unroll
    for (int sr = 0; sr < 4; ++sr) {
        ls4[sr] += __shfl_xor(ls4[sr], 1);
        ls4[sr] += __shfl_xor(ls4[sr], 2);
        ls4[sr] += __shfl_xor(ls4[sr], 4);
        ls4[sr] += __shfl_xor(ls4[sr], 8);
    }
    if (lm == 0) {
        #pragma unroll
        for (int sr = 0; sr < 4; ++sr)
            lsLDS[w][4 * sr + g16] = ls4[sr];
    }
    const f32x4 lsq = *(const f32x4*)&lsLDS[w][4 * q];   // rows 4q..4q+3

    // ---- epilogue: agg = acc/l, LDS round-trip to A-layout, @W_lin^T, sigmoid
    unsigned short* aggl = &Plds[w][0][0];   // reuse P slice, stride 72
    #pragma unroll
    for (int nt = 0; nt < 4; ++nt)
        #pragma unroll
        for (int r = 0; r < 4; ++r)
            aggl[(q * 4 + r) * 72 + nt * 16 + i15] = f2bf(acc[nt][r] / lsq[r]);

    f32x4 d2[4] = {};
    #pragma unroll
    for (int s = 0; s < 2; ++s) {
        bf16x8 af = *(const bf16x8*)&aggl[i15 * 72 + s * 32 + q * 8];
        #pragma unroll
        for (int nt = 0; nt < 4; ++nt) {
            const float* wp = Wlin + (size_t)(nt * 16 + i15) * C_ + s * 32 + q * 8;
            f32x4 w0 = *(const f32x4*)wp;
            f32x4 w1 = *(const f32x4*)(wp + 4);
            bf16x8 bfr;
            #pragma unroll
            for (int jj = 0; jj < 4; ++jj) { bfr[jj] = (__bf16)w0[jj]; bfr[4 + jj] = (__bf16)w1[jj]; }
            d2[nt] = __builtin_amdgcn_mfma_f32_16x16x32_bf16(af, bfr, d2[nt], 0, 0, 0);
        }
    }
    float* orow = out + ((size_t)bp * N_ + ibase) * C_;
    #pragma unroll
    for (int nt = 0; nt < 4; ++nt)
        #pragma unroll
        for (int r = 0; r < 4; ++r)
            orow[(size_t)(q * 4 + r) * C_ + nt * 16 + i15] =
                1.f / (1.f + __expf(-d2[nt][r]));
}

extern "C" void kernel_launch(void* const* d_in, const int* in_sizes, int n_in,
                              void* d_out, int out_size, void* d_ws, size_t ws_size,
                              hipStream_t stream) {
    const float* x    = (const float*)d_in[0];
    const float* Ag   = (const float*)d_in[1];
    const float* Wemb = (const float*)d_in[2];
    const float* a1   = (const float*)d_in[3];
    const float* a2   = (const float*)d_in[4];
    const float* Wlin = (const float*)d_in[5];
    float* out  = (float*)d_out;
    float* outA = out + (size_t)BP_ * N_ * C_;   // tuple output #2: A passthrough

    // ws layout (~6.7 MB total)
    float* s1g = (float*)d_ws;                               // 48K f32
    float* s2g = s1g + BP_ * N_;                             // 48K f32
    float* M2part = s2g + BP_ * N_;                          // 48*64 f32
    unsigned short* xT = (unsigned short*)(M2part + BP_ * 64);   // 6.3MB bf16 frags

    gat_pre<<<dim3(16, BP_), dim3(256), 0, stream>>>(x, Wemb, a1, a2,
                                                     s1g, s2g, xT, M2part);
    gat_fused<<<dim3(16, BP_), dim3(256), 0, stream>>>(Ag, outA, xT, s1g, s2g,
                                                       M2part, Wlin, out);
}